// Round 7
// baseline (173.908 us; speedup 1.0000x reference)
//
#include <hip/hip_runtime.h>
#include <stdint.h>

#define HIDDEN 1024
#define SEQ 4096
#define BATCH 4
#define HEADS 16
#define HDIM 64
#define M_TOT (BATCH * SEQ)   // 16384
#define NCH 4                 // split-S chunks for kv reduction
#define NT64 16               // K-steps of 64

typedef __bf16 bf16x8 __attribute__((ext_vector_type(8)));
typedef float f32x4 __attribute__((ext_vector_type(4)));
typedef unsigned short u16x8 __attribute__((ext_vector_type(8)));

static __device__ __forceinline__ unsigned short f2bf(float f) {
  union { float f; uint32_t u; } v; v.f = f;
  uint32_t u = v.u;
  uint32_t r = (u + 0x7fffu + ((u >> 16) & 1u)) >> 16;
  return (unsigned short)r;
}
static __device__ __forceinline__ void load_lds16(const void* g, void* l) {
  __builtin_amdgcn_global_load_lds(
      (__attribute__((address_space(1))) void*)(g),
      (__attribute__((address_space(3))) void*)(l), 16, 0, 0);
}

// ---------------- fused prep kernel ----------------
__global__ __launch_bounds__(256) void prep_k(
    const float* __restrict__ x, unsigned short* __restrict__ xb,
    const float* __restrict__ Wk, const float* __restrict__ Wv,
    unsigned short* __restrict__ Bt,
    const float* __restrict__ bk, const float* __restrict__ bv,
    float* __restrict__ bkv,
    const float* __restrict__ mask, float* __restrict__ norm) {
  const int bid = blockIdx.x;
  const int tid = threadIdx.x;
  __shared__ float ts[64][65];
  if (bid < 8192) {
    int idx = bid * 256 + tid;
    const float4* xv = (const float4*)x;
    float4 a = xv[(size_t)idx * 2];
    float4 b = xv[(size_t)idx * 2 + 1];
    u16x8 o;
    o[0] = f2bf(a.x); o[1] = f2bf(a.y); o[2] = f2bf(a.z); o[3] = f2bf(a.w);
    o[4] = f2bf(b.x); o[5] = f2bf(b.y); o[6] = f2bf(b.z); o[7] = f2bf(b.w);
    *(u16x8*)(xb + (size_t)idx * 8) = o;
  } else if (bid < 8704) {
    int idx = bid - 8192;
    int z = idx >> 8, rem = idx & 255;
    const float* W = z ? Wv : Wk;
    unsigned short* out = Bt + (size_t)z * HIDDEN * HIDDEN;
    int n0 = (rem & 15) * 64, k0 = (rem >> 4) * 64;
    int c = tid & 63, rq = tid >> 6;
    for (int i = 0; i < 16; ++i) {
      int r = i * 4 + rq;
      ts[r][c] = W[(size_t)(k0 + r) * HIDDEN + n0 + c];
    }
    __syncthreads();
    for (int i = 0; i < 16; ++i) {
      int n = i * 4 + rq;
      out[(size_t)(n0 + n) * HIDDEN + k0 + c] = f2bf(ts[c][n]);
    }
  } else if (bid < 8712) {
    int i = (bid - 8704) * 256 + tid;
    bkv[i] = (i < HIDDEN) ? bk[i] : bv[i - HIDDEN];
  } else {
    int b = bid - 8712;
    float s = 0.f;
    for (int i = tid; i < SEQ; i += 256) s += mask[b * SEQ + i];
    for (int off = 32; off; off >>= 1) s += __shfl_down(s, off);
    __shared__ float wsum[4];
    if ((tid & 63) == 0) wsum[tid >> 6] = s;
    __syncthreads();
    if (tid == 0) {
      float t = wsum[0] + wsum[1] + wsum[2] + wsum[3];
      norm[b] = rsqrtf(t * (float)HDIM);
    }
  }
}

// ---------------- 256x256 GEMM, m201-literal phase discipline -------------------
// Per phase: {ds_read subtile ∥ stage -> sched_bar -> [lgkm(8)] -> BAR -> lgkm(0)
//             -> sched_bar -> setprio(1) -> 16 MFMA -> setprio(0) -> sched_bar -> BAR}
// Stage slots (liveness >= 2 barriers before write, all verified):
//   P1(t): A0(t+1) -> buf(t+1)&1  (last read P3(t-1))
//   P2(t): A1(t+1) -> buf(t+1)&1  (last read P3(t-1))
//   P3(t): B0(t+2) -> buf t&1     (last read P2(t) by wn=0,1)
//   P4(t): B1(t+2) -> buf t&1     (last read P2(t) by wn=2,3)
// End-of-P4(t) vmcnt(4): outstanding {A0,A1(t+1),B0,B1(t+2)}=8; retires A(t+1).
template <int OUT_MODE, int PER_BATCH_B>
__global__ __launch_bounds__(512, 2) void gemm256_k(
    const unsigned short* __restrict__ A, const unsigned short* __restrict__ Bt,
    const float* __restrict__ bias, const float* __restrict__ mask,
    void* __restrict__ C, int ldc, int nbn) {
  __shared__ unsigned short smem[65536];  // 128 KiB: 2 bufs x (A 256x64 + B 256x64)

  const int nwg = gridDim.x;
  const int bid = blockIdx.x;
  const int wg = (bid & 7) * (nwg >> 3) + (bid >> 3);  // XCD swizzle (nwg%8==0)
  const int row0 = (wg / nbn) * 256;
  const int col0 = (wg % nbn) * 256;

  const unsigned short* Bbase = Bt;
  const float* biasbase = bias;
  if (PER_BATCH_B) {
    int b = row0 >> 12;
    Bbase = Bt + (size_t)b * HIDDEN * HIDDEN;
    biasbase = bias + b * HIDDEN;
  }

  const int tid = threadIdx.x;
  const int wave = tid >> 6;
  const int lane = tid & 63;
  const int wm = wave >> 2;   // 0..1 (M half)
  const int wn = wave & 3;    // 0..3 (N quarter)
  const int lr = lane & 15;
  const int hi = lane >> 4;   // 0..3

  // staging: linear LDS dest, inverse-swizzled global source (chunk ^= row&7)
  const int srow = tid >> 3;                        // 0..63
  const int scol = ((tid & 7) ^ (srow & 7)) * 8;    // (row&7)-XORed 16B chunk
  const unsigned short* sA = A + (size_t)(row0 + srow) * HIDDEN + scol;
  const unsigned short* sB = Bbase + (size_t)(col0 + srow) * HIDDEN + scol;
  const int ldst = tid * 8;

#define STAGE(half, tt, isB) { \
    int dst_ = ((tt)&1) * 32768 + (isB) * 16384 + (half) * 8192 + ldst; \
    const unsigned short* src_ = ((isB) ? sB : sA) + (size_t)(half) * 128 * HIDDEN + (tt) * 64; \
    load_lds16(src_, &smem[dst_]); \
    load_lds16(src_ + (size_t)64 * HIDDEN, &smem[dst_ + 4096]); }

  // swizzled frag read offsets: row ra -> ra*64 + ((k8 ^ (ra&7))*8); ra&7 == lr&7
  const int chunk0 = (hi ^ (lr & 7)) * 8;          // kh=0
  const int chunk1 = ((4 + hi) ^ (lr & 7)) * 8;    // kh=1
  const int arow = (wm * 128 + lr) * 64;           // + rf*1024 (+4096 for m-half 1)
  const int brow = 16384 + (wn * 64 + lr) * 64;    // + cf*1024 (+2048 for n-sub 1)

  f32x4 acc[8][4];
#pragma unroll
  for (int i = 0; i < 8; ++i)
#pragma unroll
    for (int j = 0; j < 4; ++j) acc[i][j] = (f32x4){0.f, 0.f, 0.f, 0.f};

  // prologue: t0 full (8 loads) + B(1) (4 loads); vmcnt(4) => t0 landed
  STAGE(0, 0, 0) STAGE(1, 0, 0) STAGE(0, 0, 1) STAGE(1, 0, 1)
  STAGE(0, 1, 1) STAGE(1, 1, 1)
  asm volatile("s_waitcnt vmcnt(4)");
  __builtin_amdgcn_s_barrier();

#define MFMA16(AMBASE, BF) \
  { __builtin_amdgcn_s_setprio(1); \
    _Pragma("unroll") \
    for (int rf = 0; rf < 4; ++rf) \
      _Pragma("unroll") \
      for (int cf = 0; cf < 2; ++cf) \
        _Pragma("unroll") \
        for (int kh = 0; kh < 2; ++kh) \
          acc[(AMBASE) + rf][((BF) ? 2 : 0) + cf] = __builtin_amdgcn_mfma_f32_16x16x32_bf16( \
              af[rf][kh], ((BF) ? b1f : b0f)[cf][kh], acc[(AMBASE) + rf][((BF) ? 2 : 0) + cf], 0, 0, 0); \
    __builtin_amdgcn_s_setprio(0); }

  bf16x8 af[4][2], b0f[2][2], b1f[2][2];
  for (int t = 0; t < NT64; ++t) {
    const int bb = (t & 1) * 32768;
    // ---- P1: reads A-m0(8) + B-sub0(4); stage A0(t+1); MFMA (m0,n0) ----
#pragma unroll
    for (int rf = 0; rf < 4; ++rf) {
      af[rf][0] = *(const bf16x8*)&smem[bb + arow + rf * 1024 + chunk0];
      af[rf][1] = *(const bf16x8*)&smem[bb + arow + rf * 1024 + chunk1];
    }
#pragma unroll
    for (int cf = 0; cf < 2; ++cf) {
      b0f[cf][0] = *(const bf16x8*)&smem[bb + brow + cf * 1024 + chunk0];
      b0f[cf][1] = *(const bf16x8*)&smem[bb + brow + cf * 1024 + chunk1];
    }
    if (t + 1 < NT64) STAGE(0, t + 1, 0)
    __builtin_amdgcn_sched_barrier(0);
    asm volatile("s_waitcnt lgkmcnt(8)");
    __builtin_amdgcn_s_barrier();
    asm volatile("s_waitcnt lgkmcnt(0)");
    __builtin_amdgcn_sched_barrier(0);
    MFMA16(0, 0)
    __builtin_amdgcn_sched_barrier(0);
    __builtin_amdgcn_s_barrier();
    // ---- P2: reads B-sub1(4); stage A1(t+1); MFMA (m0,n1) ----
#pragma unroll
    for (int cf = 0; cf < 2; ++cf) {
      b1f[cf][0] = *(const bf16x8*)&smem[bb + brow + 2048 + cf * 1024 + chunk0];
      b1f[cf][1] = *(const bf16x8*)&smem[bb + brow + 2048 + cf * 1024 + chunk1];
    }
    if (t + 1 < NT64) STAGE(1, t + 1, 0)
    __builtin_amdgcn_sched_barrier(0);
    __builtin_amdgcn_s_barrier();
    asm volatile("s_waitcnt lgkmcnt(0)");
    __builtin_amdgcn_sched_barrier(0);
    MFMA16(0, 1)
    __builtin_amdgcn_sched_barrier(0);
    __builtin_amdgcn_s_barrier();
    // ---- P3: reads A-m1(8); stage B0(t+2); MFMA (m1,n0) ----
#pragma unroll
    for (int rf = 0; rf < 4; ++rf) {
      af[rf][0] = *(const bf16x8*)&smem[bb + arow + 4096 + rf * 1024 + chunk0];
      af[rf][1] = *(const bf16x8*)&smem[bb + arow + 4096 + rf * 1024 + chunk1];
    }
    if (t + 2 < NT64) STAGE(0, t + 2, 1)
    __builtin_amdgcn_sched_barrier(0);
    __builtin_amdgcn_s_barrier();
    asm volatile("s_waitcnt lgkmcnt(0)");
    __builtin_amdgcn_sched_barrier(0);
    MFMA16(4, 0)
    __builtin_amdgcn_sched_barrier(0);
    __builtin_amdgcn_s_barrier();
    // ---- P4: stage B1(t+2); MFMA (m1,n1); counted vmcnt ----
    if (t + 2 < NT64) STAGE(1, t + 2, 1)
    __builtin_amdgcn_sched_barrier(0);
    __builtin_amdgcn_s_barrier();
    MFMA16(4, 1)
    __builtin_amdgcn_sched_barrier(0);
    if (t < NT64 - 2) asm volatile("s_waitcnt vmcnt(4)");
    else              asm volatile("s_waitcnt vmcnt(0)");
    __builtin_amdgcn_s_barrier();
  }
#undef MFMA16

  // ---- epilogue ----
  float bcol[4];
#pragma unroll
  for (int an = 0; an < 4; ++an)
    bcol[an] = biasbase[col0 + wn * 64 + (an >> 1) * 32 + (an & 1) * 16 + lr];

  if (OUT_MODE == 2) {
    // transposed bf16 store: KVt[(n*4+b)*4096 + s]
    const int b = row0 >> 12;
    const int s0 = (row0 & 4095) + wm * 128;
    unsigned short* wt = &smem[wave * 4096];
    unsigned short* KVt = (unsigned short*)C;
#pragma unroll
    for (int half = 0; half < 2; ++half) {
#pragma unroll
      for (int am4 = 0; am4 < 4; ++am4) {
#pragma unroll
        for (int j = 0; j < 4; ++j) {
          int r = am4 * 16 + hi * 4 + j;  // 0..63 within half
          float mrow = mask[row0 + wm * 128 + half * 64 + r];
#pragma unroll
          for (int an = 0; an < 4; ++an) {
            int c = (an >> 1) * 32 + (an & 1) * 16 + lr;
            wt[c * 64 + (r ^ ((c & 7) << 3))] =
                f2bf((acc[half * 4 + am4][an][j] + bcol[an]) * mrow);
          }
        }
      }
      asm volatile("s_waitcnt lgkmcnt(0)" ::: "memory");
#pragma unroll
      for (int i = 0; i < 8; ++i) {
        int flat = i * 64 + lane;
        int c = flat >> 3, rq = flat & 7;
        uint4 vv = *(const uint4*)&wt[c * 64 + ((rq * 8) ^ ((c & 7) << 3))];
        *(uint4*)&KVt[((size_t)(col0 + wn * 64 + c) * 4 + b) * 4096 + s0 + half * 64 + rq * 8] = vv;
      }
      asm volatile("s_waitcnt lgkmcnt(0)" ::: "memory");
    }
  } else {
    // direct nontemporal f32 stores (out is never re-read)
    float* Cg = (float*)C;
#pragma unroll
    for (int am = 0; am < 8; ++am) {
      int rbase = (am >> 2) * 64 + (am & 3) * 16 + hi * 4;
#pragma unroll
      for (int j = 0; j < 4; ++j) {
        int r = rbase + j;
        float mrow = mask[row0 + wm * 128 + r];
#pragma unroll
        for (int an = 0; an < 4; ++an) {
          int c = (an >> 1) * 32 + (an & 1) * 16 + lr;
          __builtin_nontemporal_store(
              (acc[am][an][j] + bcol[an]) * mrow,
              &Cg[(size_t)(row0 + wm * 128 + r) * ldc + col0 + wn * 64 + c]);
        }
      }
    }
  }
#undef STAGE
}

// ---------------- kv partials via MFMA: part[ch][bh][d][e] = sum_s Kt[d][s]*Vt[e][s] ----
__global__ __launch_bounds__(256) void kvpart2_k(const unsigned short* __restrict__ KVt,
                                                 float* __restrict__ part) {
  const int bh = blockIdx.x, ch = blockIdx.y;
  const int b = bh >> 4, h = bh & 15;
  __shared__ unsigned short tl[32768];  // 4 bufs x (A[64][64] + B[64][64]) = 64 KiB
  const int tid = threadIdx.x;
  const int wave = tid >> 6, lane = tid & 63;
  const int lr = lane & 15, hi = lane >> 4;

  const int r0 = tid >> 3;
  const int cc0 = ((tid & 7) ^ (r0 & 7)) * 8;
  const int r1 = 32 + r0;
  const int cc1 = ((tid & 7) ^ (r1 & 7)) * 8;
  const unsigned short* A0 = KVt + ((size_t)(h * 64 + r0) * 4 + b) * 4096 + ch * 1024 + cc0;
  const unsigned short* A1 = KVt + ((size_t)(h * 64 + r1) * 4 + b) * 4096 + ch * 1024 + cc1;
  const unsigned short* B0 = KVt + ((size_t)(1024 + h * 64 + r0) * 4 + b) * 4096 + ch * 1024 + cc0;
  const unsigned short* B1 = KVt + ((size_t)(1024 + h * 64 + r1) * 4 + b) * 4096 + ch * 1024 + cc1;

#define KSTAGE(tt) { int bb2 = ((tt) & 3) * 8192; \
    load_lds16(A0 + (tt) * 64, &tl[bb2 + tid * 8]); \
    load_lds16(A1 + (tt) * 64, &tl[bb2 + 2048 + tid * 8]); \
    load_lds16(B0 + (tt) * 64, &tl[bb2 + 4096 + tid * 8]); \
    load_lds16(B1 + (tt) * 64, &tl[bb2 + 6144 + tid * 8]); }

  const int ra = wave * 16 + lr;
  const int aoff = ra * 64;
  const int ach0 = (hi ^ (ra & 7)) * 8, ach1 = ((4 + hi) ^ (ra & 7)) * 8;

  f32x4 acc4[4];
#pragma unroll
  for (int nt = 0; nt < 4; ++nt) acc4[nt] = (f32x4){0.f, 0.f, 0.f, 0.f};

  KSTAGE(0) KSTAGE(1)
  asm volatile("s_waitcnt vmcnt(4)" ::: "memory");
  __builtin_amdgcn_s_barrier();
  for (int t = 0; t < 16; ++t) {
    const int bb = (t & 3) * 8192;
    if (t + 2 < 16) KSTAGE(t + 2)
    bf16x8 a0 = *(const bf16x8*)&tl[bb + aoff + ach0];
    bf16x8 a1 = *(const bf16x8*)&tl[bb + aoff + ach1];
    bf16x8 bf0[4], bf1[4];
#pragma unroll
    for (int nt = 0; nt < 4; ++nt) {
      int rb = nt * 16 + lr;
      bf0[nt] = *(const bf16x8*)&tl[bb + 4096 + rb * 64 + ((hi ^ (rb & 7)) * 8)];
      bf1[nt] = *(const bf16x8*)&tl[bb + 4096 + rb * 64 + (((4 + hi) ^ (rb & 7)) * 8)];
    }
#pragma unroll
    for (int nt = 0; nt < 4; ++nt) {
      acc4[nt] = __builtin_amdgcn_mfma_f32_16x16x32_bf16(a0, bf0[nt], acc4[nt], 0, 0, 0);
      acc4[nt] = __builtin_amdgcn_mfma_f32_16x16x32_bf16(a1, bf1[nt], acc4[nt], 0, 0, 0);
    }
    if (t < 14) asm volatile("s_waitcnt vmcnt(4)" ::: "memory");
    else        asm volatile("s_waitcnt vmcnt(0)" ::: "memory");
    __builtin_amdgcn_s_barrier();
  }
  float* dst = part + ((size_t)ch * 64 + bh) * 4096;
#pragma unroll
  for (int nt = 0; nt < 4; ++nt)
#pragma unroll
    for (int j = 0; j < 4; ++j)
      dst[(wave * 16 + hi * 4 + j) * 64 + nt * 16 + lr] = acc4[nt][j];
#undef KSTAGE
}

// kv[bh*4096 + d*64 + e] = norm[b] * sum_ch part  (grid 1024 x 256)
__global__ void kvreduce_k(const float* __restrict__ part, const float* __restrict__ norm,
                           float* __restrict__ kv) {
  int idx = blockIdx.x * 256 + threadIdx.x;
  int b = idx >> 16;
  float s = 0.f;
#pragma unroll
  for (int ch = 0; ch < NCH; ++ch) s += part[(size_t)ch * 262144 + idx];
  kv[idx] = s * norm[b];
}

__global__ void bias2_k(const float* __restrict__ bq, const float* __restrict__ kv,
                        float* __restrict__ bias2) {
  int idx = blockIdx.x * 256 + threadIdx.x;
  int b = idx >> 10, n = idx & 1023, h = n >> 6, e = n & 63;
  const float* kvp = kv + ((size_t)(b * 16 + h)) * 4096 + e;
  float s = 0.f;
#pragma unroll
  for (int d = 0; d < 64; ++d) s += bq[h * 64 + d] * kvp[d * 64];
  bias2[idx] = s;
}

__global__ __launch_bounds__(128) void wprime_k(const float* __restrict__ Wq,
                                                const float* __restrict__ kv,
                                                unsigned short* __restrict__ Wpt) {
  int bh = blockIdx.y, b = bh >> 4, h = bh & 15;
  int c0 = blockIdx.x * 128;
  __shared__ float wqs[128][65];
  __shared__ float kvs[64][64];
  int tid = threadIdx.x;
  for (int i = 0; i < 32; ++i) {
    int idx = i * 128 + tid;
    ((float*)kvs)[idx] = kv[(size_t)bh * 4096 + idx];
  }
  int rr = tid >> 6, cc = tid & 63;
  for (int i = 0; i < 64; ++i) {
    int r = i * 2 + rr;
    wqs[r][cc] = Wq[(size_t)(c0 + r) * HIDDEN + h * 64 + cc];
  }
  __syncthreads();
  float acc[64];
#pragma unroll
  for (int e = 0; e < 64; ++e) acc[e] = 0.f;
  for (int d = 0; d < 64; ++d) {
    float w = wqs[tid][d];
#pragma unroll
    for (int e4 = 0; e4 < 64; e4 += 4) {
      f32x4 kvv = *(const f32x4*)&kvs[d][e4];
      acc[e4 + 0] += w * kvv[0];
      acc[e4 + 1] += w * kvv[1];
      acc[e4 + 2] += w * kvv[2];
      acc[e4 + 3] += w * kvv[3];
    }
  }
  unsigned short* dst = Wpt + (size_t)b * HIDDEN * HIDDEN + (size_t)(h * 64) * HIDDEN + (c0 + tid);
#pragma unroll
  for (int e = 0; e < 64; ++e) dst[(size_t)e * HIDDEN] = f2bf(acc[e]);
}

// ---------------- launch ----------------
extern "C" void kernel_launch(void* const* d_in, const int* in_sizes, int n_in,
                              void* d_out, int out_size, void* d_ws, size_t ws_size,
                              hipStream_t stream) {
  const float* x = (const float*)d_in[0];
  const float* mask = (const float*)d_in[1];
  const float* Wq = (const float*)d_in[2];
  const float* bq = (const float*)d_in[3];
  const float* Wk = (const float*)d_in[4];
  const float* bk = (const float*)d_in[5];
  const float* Wv = (const float*)d_in[6];
  const float* bv = (const float*)d_in[7];
  float* out = (float*)d_out;

  char* w = (char*)d_ws;
  unsigned short* xb = (unsigned short*)w;  w += (size_t)M_TOT * HIDDEN * 2;           // 32 MiB
  unsigned short* Bt = (unsigned short*)w;  w += (size_t)2048 * HIDDEN * 2;            // 4 MiB
  unsigned short* KVt = (unsigned short*)w; w += (size_t)2048 * BATCH * SEQ * 2;       // 64 MiB
  float* part = (float*)w;                  w += (size_t)NCH * 64 * 4096 * 4;          // 4 MiB
  float* kv = (float*)w;                    w += (size_t)64 * 4096 * 4;                // 1 MiB
  unsigned short* Wpt = (unsigned short*)w; w += (size_t)BATCH * HIDDEN * HIDDEN * 2;  // 8 MiB
  float* bkv = (float*)w;                   w += 2048 * 4;
  float* bias2 = (float*)w;                 w += 4096 * 4;
  float* norm = (float*)w;                  w += 64;

  prep_k<<<dim3(8716), dim3(256), 0, stream>>>(x, xb, Wk, Wv, Bt, bk, bv, bkv, mask, norm);
  // KV projection: M=16384, N=2048, K=1024 -> 512 blocks; writes transposed KVt
  gemm256_k<2, 0><<<dim3(512), dim3(512), 0, stream>>>(xb, Bt, bkv, mask, (void*)KVt, 0, 8);
  kvpart2_k<<<dim3(64, NCH), dim3(256), 0, stream>>>(KVt, part);
  kvreduce_k<<<dim3(1024), dim3(256), 0, stream>>>(part, norm, kv);
  bias2_k<<<dim3(16), dim3(256), 0, stream>>>(bq, kv, bias2);
  wprime_k<<<dim3(8, 64), dim3(128), 0, stream>>>(Wq, kv, Wpt);
  // out GEMM: M=16384, N=1024, K=1024 -> 256 blocks; f32 out
  gemm256_k<0, 1><<<dim3(256), dim3(512), 0, stream>>>(xb, Wpt, bias2, mask, (void*)out, 1024, 4);
}